// Round 16
// baseline (151.416 us; speedup 1.0000x reference)
//
#include <hip/hip_runtime.h>
#include <hip/hip_bf16.h>

#define HW 3136

typedef short s16x8 __attribute__((ext_vector_type(8)));
typedef float f32x4 __attribute__((ext_vector_type(4)));
typedef unsigned short us4 __attribute__((ext_vector_type(4)));
typedef unsigned short us8 __attribute__((ext_vector_type(8)));

__device__ inline unsigned short f2bf(float f) {
  union { float f; unsigned int u; } v; v.f = f;
  unsigned int r = v.u + 0x7fff + ((v.u >> 16) & 1);
  return (unsigned short)(r >> 16);
}
__device__ inline float bf2f(unsigned short b) {
  union { unsigned int u; float f; } v; v.u = (unsigned int)b << 16;
  return v.f;
}

// ---------------------------------------------------------------------------
// Weight prep. y=0..2: q_w/k_w/v_w -> plain bf16. y=3: o_w -> hi/lo bf16 pair.
// ---------------------------------------------------------------------------
__global__ __launch_bounds__(256) void wconv_kernel(
    const float* __restrict__ w0, const float* __restrict__ w1,
    const float* __restrict__ w2, const float* __restrict__ w3,
    unsigned short* __restrict__ o0, unsigned short* __restrict__ o1,
    unsigned short* __restrict__ o2, unsigned short* __restrict__ o3h,
    unsigned short* __restrict__ o3l) {
  int i = blockIdx.x * 256 + threadIdx.x;
  int y = blockIdx.y;
  if (y < 3) {
    const float* s = (y == 0) ? w0 : (y == 1) ? w1 : w2;
    unsigned short* d = (y == 0) ? o0 : (y == 1) ? o1 : o2;
    d[i] = f2bf(s[i]);
  } else {
    float x = w3[i];
    unsigned short hi = f2bf(x);
    o3h[i] = hi;
    o3l[i] = f2bf(x - bf2f(hi));
  }
}

// ---------------------------------------------------------------------------
// q-projection MFMA, fused transpose, o-split 2. grid (98, 8), block 128.
// ---------------------------------------------------------------------------
__global__ __launch_bounds__(128) void gemm_q_kernel(
    const float* __restrict__ x, const unsigned short* __restrict__ Wq,
    const float* __restrict__ bias, float* __restrict__ Outf,
    unsigned short* __restrict__ Outb) {
  int by = blockIdx.y;
  int b = by >> 1, oh = by & 1;
  int t = threadIdx.x;
  int w = t >> 6, l = t & 63;
  int lq = l & 15, h = l >> 4;
  int p = blockIdx.x * 32 + w * 16 + lq;

  union S8 { s16x8 v; unsigned short u[8]; };
  S8 bfr[4];
  const float* xs = x + (size_t)b * 128 * HW + p;
  #pragma unroll
  for (int k = 0; k < 4; ++k)
    #pragma unroll
    for (int j = 0; j < 8; ++j)
      bfr[k].u[j] = f2bf(xs[(size_t)(k * 32 + h * 8 + j) * HW]);

  f32x4 acc[4] = {};
  #pragma unroll
  for (int k = 0; k < 4; ++k) {
    #pragma unroll
    for (int ot = 0; ot < 4; ++ot) {
      int og = oh * 4 + ot;
      s16x8 af = *(const s16x8*)&Wq[(size_t)(og * 16 + lq) * 128 + k * 32 + h * 8];
      acc[ot] = __builtin_amdgcn_mfma_f32_16x16x32_bf16(af, bfr[k].v, acc[ot], 0, 0, 0);
    }
  }

  size_t cb = (size_t)b * 128 * HW;
  #pragma unroll
  for (int ot = 0; ot < 4; ++ot) {
    int og = oh * 4 + ot;
    float4 bv = *(const float4*)&bias[og * 16 + h * 4];
    float r[4] = {acc[ot][0] + bv.x, acc[ot][1] + bv.y,
                  acc[ot][2] + bv.z, acc[ot][3] + bv.w};
    #pragma unroll
    for (int i = 0; i < 4; ++i)
      Outf[cb + (size_t)(og * 16 + h * 4 + i) * HW + p] = r[i];
    const float S = 0.25503968151135f;  // rsqrt(32)*log2e
    us4 rb;
    #pragma unroll
    for (int i = 0; i < 4; ++i) rb[i] = f2bf(r[i] * S);
    *(us4*)&Outb[((size_t)b * HW + p) * 128 + og * 16 + h * 4] = rb;
  }
}

// ---------------------------------------------------------------------------
// Fused K+V projection, o-split 2. grid (98, 8), block 128.
// ---------------------------------------------------------------------------
__global__ __launch_bounds__(128) void gemm_kv_kernel(
    const unsigned short* __restrict__ InT, const unsigned short* __restrict__ Wk,
    const unsigned short* __restrict__ Wv, const float* __restrict__ k_b,
    const float* __restrict__ v_b, unsigned short* __restrict__ kbT,
    unsigned short* __restrict__ vb) {
  int by = blockIdx.y;
  int b = by >> 1, oh = by & 1;
  int t = threadIdx.x;
  int w = t >> 6, l = t & 63;
  int lq = l & 15, h = l >> 4;
  int p = blockIdx.x * 32 + w * 16 + lq;

  s16x8 bfr[4];
  const unsigned short* bsrc = InT + ((size_t)b * HW + p) * 128 + h * 8;
  #pragma unroll
  for (int k = 0; k < 4; ++k) bfr[k] = *(const s16x8*)&bsrc[k * 32];

  {
    f32x4 acc[4] = {};
    #pragma unroll
    for (int k = 0; k < 4; ++k) {
      #pragma unroll
      for (int ot = 0; ot < 4; ++ot) {
        int og = oh * 4 + ot;
        s16x8 af = *(const s16x8*)&Wk[(size_t)(og * 16 + lq) * 128 + k * 32 + h * 8];
        acc[ot] = __builtin_amdgcn_mfma_f32_16x16x32_bf16(af, bfr[k], acc[ot], 0, 0, 0);
      }
    }
    #pragma unroll
    for (int ot = 0; ot < 4; ++ot) {
      int og = oh * 4 + ot;
      float4 bv = *(const float4*)&k_b[og * 16 + h * 4];
      us4 rb;
      #pragma unroll
      for (int i = 0; i < 4; ++i) rb[i] = f2bf(acc[ot][i] + bv[i]);
      *(us4*)&kbT[((size_t)b * HW + p) * 128 + og * 16 + h * 4] = rb;
    }
  }
  {
    f32x4 acc[4] = {};
    #pragma unroll
    for (int k = 0; k < 4; ++k) {
      #pragma unroll
      for (int ot = 0; ot < 4; ++ot) {
        int og = oh * 4 + ot;
        s16x8 af = *(const s16x8*)&Wv[(size_t)(og * 16 + lq) * 128 + k * 32 + h * 8];
        acc[ot] = __builtin_amdgcn_mfma_f32_16x16x32_bf16(af, bfr[k], acc[ot], 0, 0, 0);
      }
    }
    size_t cb = (size_t)b * 128 * HW;
    #pragma unroll
    for (int ot = 0; ot < 4; ++ot) {
      int og = oh * 4 + ot;
      float4 bv = *(const float4*)&v_b[og * 16 + h * 4];
      #pragma unroll
      for (int i = 0; i < 4; ++i)
        vb[cb + (size_t)(og * 16 + h * 4 + i) * HW + p] = f2bf(acc[ot][i] + bv[i]);
    }
  }
}

// ---------------------------------------------------------------------------
// o-projection MFMA hi/lo, o-split 2. grid (98, 8), block 128.
// ---------------------------------------------------------------------------
__global__ __launch_bounds__(128) void o_gemm_kernel(
    const unsigned short* __restrict__ AHi, const unsigned short* __restrict__ ALo,
    const unsigned short* __restrict__ WHi, const unsigned short* __restrict__ WLo,
    const float* __restrict__ bias, float* __restrict__ Outf) {
  int by = blockIdx.y;
  int b = by >> 1, oh = by & 1;
  int t = threadIdx.x;
  int w = t >> 6, l = t & 63;
  int lq = l & 15, h = l >> 4;
  int p = blockIdx.x * 32 + w * 16 + lq;

  s16x8 bH[4], bL[4];
  const unsigned short* bsH = AHi + ((size_t)b * HW + p) * 128 + h * 8;
  const unsigned short* bsL = ALo + ((size_t)b * HW + p) * 128 + h * 8;
  #pragma unroll
  for (int k = 0; k < 4; ++k) {
    bH[k] = *(const s16x8*)&bsH[k * 32];
    bL[k] = *(const s16x8*)&bsL[k * 32];
  }

  f32x4 acc[4] = {};
  #pragma unroll
  for (int k = 0; k < 4; ++k) {
    #pragma unroll
    for (int ot = 0; ot < 4; ++ot) {
      int og = oh * 4 + ot;
      size_t wi = (size_t)(og * 16 + lq) * 128 + k * 32 + h * 8;
      s16x8 aH = *(const s16x8*)&WHi[wi];
      s16x8 aL = *(const s16x8*)&WLo[wi];
      acc[ot] = __builtin_amdgcn_mfma_f32_16x16x32_bf16(aH, bH[k], acc[ot], 0, 0, 0);
      acc[ot] = __builtin_amdgcn_mfma_f32_16x16x32_bf16(aH, bL[k], acc[ot], 0, 0, 0);
      acc[ot] = __builtin_amdgcn_mfma_f32_16x16x32_bf16(aL, bH[k], acc[ot], 0, 0, 0);
    }
  }

  size_t cb = (size_t)b * 128 * HW;
  #pragma unroll
  for (int ot = 0; ot < 4; ++ot) {
    int og = oh * 4 + ot;
    float4 bv = *(const float4*)&bias[og * 16 + h * 4];
    #pragma unroll
    for (int i = 0; i < 4; ++i)
      Outf[cb + (size_t)(og * 16 + h * 4 + i) * HW + p] = acc[ot][i] + bv[i];
  }
}

// ---------------------------------------------------------------------------
// Offset branch v3 (unchanged): 1024 threads per (bg, h-row). grid (8, 56).
// ---------------------------------------------------------------------------
__global__ __launch_bounds__(1024) void offset_kernel(
    const float* __restrict__ q, const float* __restrict__ dw_w,
    const float* __restrict__ dw_b, const float* __restrict__ ln_g,
    const float* __restrict__ ln_b, const float* __restrict__ off_w,
    float* __restrict__ pos) {
  __shared__ float vs[64][65];
  __shared__ float mu_s[64], rs_s[64];
  __shared__ float part[16][64][2];
  int bg = blockIdx.x, h = blockIdx.y;
  int t = threadIdx.x;
  int w = t & 63;
  int cq = t >> 6;  // 0..15
  int b = bg >> 1, g = bg & 1;
  const float* qb = q + ((size_t)b * 128 + (size_t)g * 64) * HW;

  #pragma unroll
  for (int i = 0; i < 4; ++i) {
    int c = cq * 4 + i;
    float acc = dw_b[c];
    const float* qc = qb + (size_t)c * HW;
    const float* wc = dw_w + c * 49;
    #pragma unroll
    for (int ky = 0; ky < 7; ++ky) {
      int y = h + ky - 3;
      if (y >= 0 && y < 56) {
        #pragma unroll
        for (int kx = 0; kx < 7; ++kx) {
          int xx = w + kx - 3;
          if (xx >= 0 && xx < 56)
            acc += qc[y * 56 + xx] * wc[ky * 7 + kx];
        }
      }
    }
    vs[c][w] = acc;
  }
  __syncthreads();

  if (cq == 0) {
    float sum = 0.f;
    #pragma unroll 8
    for (int c = 0; c < 64; ++c) sum += vs[c][w];
    float mu = sum * 0.015625f;
    float var = 0.f;
    #pragma unroll 8
    for (int c = 0; c < 64; ++c) { float d = vs[c][w] - mu; var += d * d; }
    mu_s[w] = mu;
    rs_s[w] = rsqrtf(var * 0.015625f + 1e-5f);
  }
  __syncthreads();

  {
    float mu = mu_s[w], rstd = rs_s[w];
    float oy = 0.f, ox = 0.f;
    #pragma unroll
    for (int i = 0; i < 4; ++i) {
      int c = cq * 4 + i;
      float hn = (vs[c][w] - mu) * rstd * ln_g[c] + ln_b[c];
      hn = 0.5f * hn * (1.f + erff(hn * 0.70710678118654752f));
      oy += off_w[c] * hn;
      ox += off_w[64 + c] * hn;
    }
    part[cq][w][0] = oy;
    part[cq][w][1] = ox;
  }
  __syncthreads();

  if (cq == 0 && w < 56) {
    float oy = 0.f, ox = 0.f;
    #pragma unroll
    for (int pw = 0; pw < 16; ++pw) {
      oy += part[pw][w][0];
      ox += part[pw][w][1];
    }
    float py = tanhf(oy) * (2.0f / 56.f) + ((h + 0.5f) * (2.f / 56.f) - 1.f);
    float px = tanhf(ox) * (2.0f / 56.f) + ((w + 0.5f) * (2.f / 56.f) - 1.f);
    int idx = bg * HW + h * 56 + w;
    pos[idx * 2 + 0] = (px + 1.f) * 0.5f * 55.f;
    pos[idx * 2 + 1] = (py + 1.f) * 0.5f * 55.f;
  }
}

// ---------------------------------------------------------------------------
// Bilinear grid sample -> bf16 [b][p][128] (unchanged).
// ---------------------------------------------------------------------------
__global__ __launch_bounds__(256) void sample_kernel(
    const float* __restrict__ x, const float* __restrict__ pos,
    unsigned short* __restrict__ xsT) {
  int t = threadIdx.x;
  int p = blockIdx.x * 64 + (t & 63);
  int cg = t >> 6;
  int bg = p / HW, pp = p % HW;
  int b = bg >> 1, g = bg & 1;
  float gx = pos[2 * p], gy = pos[2 * p + 1];
  float x0f = floorf(gx), y0f = floorf(gy);
  float wx1 = gx - x0f, wx0 = 1.f - wx1;
  float wy1 = gy - y0f, wy0 = 1.f - wy1;
  int x0 = (int)x0f, y0 = (int)y0f;
  int x1 = x0 + 1, y1 = y0 + 1;
  float vx0 = (x0 >= 0 && x0 < 56) ? 1.f : 0.f;
  float vx1 = (x1 >= 0 && x1 < 56) ? 1.f : 0.f;
  float vy0 = (y0 >= 0 && y0 < 56) ? 1.f : 0.f;
  float vy1 = (y1 >= 0 && y1 < 56) ? 1.f : 0.f;
  int xc0 = min(max(x0, 0), 55), xc1 = min(max(x1, 0), 55);
  int yc0 = min(max(y0, 0), 55), yc1 = min(max(y1, 0), 55);
  float w00 = wx0 * wy0 * vx0 * vy0, w10 = wx1 * wy0 * vx1 * vy0;
  float w01 = wx0 * wy1 * vx0 * vy1, w11 = wx1 * wy1 * vx1 * vy1;
  int i00 = yc0 * 56 + xc0, i10 = yc0 * 56 + xc1;
  int i01 = yc1 * 56 + xc0, i11 = yc1 * 56 + xc1;
  const float* xb = x + ((size_t)b * 128 + (size_t)g * 64 + cg * 16) * HW;
  unsigned short tmp[16];
  #pragma unroll 4
  for (int i = 0; i < 16; ++i) {
    const float* xc = xb + (size_t)i * HW;
    tmp[i] = f2bf(w00 * xc[i00] + w10 * xc[i10] + w01 * xc[i01] + w11 * xc[i11]);
  }
  unsigned short* dst = xsT + ((size_t)b * HW + pp) * 128 + g * 64 + cg * 16;
  *(us8*)&dst[0] = *(us8*)&tmp[0];
  *(us8*)&dst[8] = *(us8*)&tmp[8];
}

// ---------------------------------------------------------------------------
// MFMA flash attention v16: 32q/wave (round-15 per-wave structure) + 2-way
// K-SPLIT within 4-wave blocks. Wave (qg = w>>1, kh = w&1): pipeline kh owns
// an independent K dbuf and processes tiles [kh*25, min(kh*25+24, 48)]
// (kh=1 runs one dummy iteration for barrier symmetry). No-max exp2 softmax
// makes partials combine linearly: one LDS exchange at the end (reusing the
// dead Klds space). Waves/CU doubles (6 -> 12) while keeping the staged-K /
// V-reg-prefetch / lgkm-only-barrier structure intact per pipeline.
// grid (49, 16), block 256 = 4 waves.
// ---------------------------------------------------------------------------
__global__ __launch_bounds__(256) void attn_mfma_kernel(
    const unsigned short* __restrict__ qT, const unsigned short* __restrict__ kT,
    const unsigned short* __restrict__ vbf, unsigned short* __restrict__ aoHi,
    unsigned short* __restrict__ aoLo) {
  __shared__ __align__(16) unsigned short Klds[2][2][64][40];  // [kh][dbuf]
  __shared__ __align__(16) unsigned short Plds[4][2][16][68];  // [wave][frag]
  const int KSTEP = 64 * 40;
  int bh = blockIdx.y;
  int b = bh >> 2, hd = bh & 3;
  int t = threadIdx.x;
  int w = t >> 6, l = t & 63;
  int qg = w >> 1, kh = w & 1;
  int lq = l & 15, h = l >> 4;
  int q0 = blockIdx.x * 64 + qg * 32;
  size_t vbase = (size_t)bh * 32 * HW;

  union S8 { s16x8 v; long long q[2]; unsigned short u[8]; };

  S8 qf0, qf1;
  qf0.v = *(const s16x8*)&qT[((size_t)b * HW + q0 + lq) * 128 + hd * 32 + h * 8];
  qf1.v = *(const s16x8*)&qT[((size_t)b * HW + q0 + 16 + lq) * 128 + hd * 32 + h * 8];

  // K staging: the 128 threads of pipeline kh (waves qg=0,1) cover 64x32.
  int pid = qg * 64 + l;
  int srow = pid >> 1, sseg = (pid & 1) * 16;
  const unsigned short* ksrc =
      kT + ((size_t)b * HW + srow) * 128 + hd * 32 + sseg;
  unsigned short* kdst = &Klds[kh][0][srow][sseg];

  const unsigned short* vl = vbf + vbase + (size_t)lq * HW + h * 8;

  f32x4 oacc0[2] = {{0.f, 0.f, 0.f, 0.f}, {0.f, 0.f, 0.f, 0.f}};
  f32x4 oacc1[2] = {{0.f, 0.f, 0.f, 0.f}, {0.f, 0.f, 0.f, 0.f}};
  float lsum0 = 0.f, lsum1 = 0.f;

  int tbase = kh * 25;  // first tile of this pipeline

  // ---- prologue: stage K(i=0), issue K(i=1), prefetch V(i=0) ----
  S8 kr0, kr1, vreg[4];
  {
    size_t o0 = (size_t)(tbase * 64) * 128;
    kr0.v = *(const s16x8*)&ksrc[o0];
    kr1.v = *(const s16x8*)&ksrc[o0 + 8];
    *(s16x8*)&kdst[0] = kr0.v;
    *(s16x8*)&kdst[8] = kr1.v;
    size_t o1 = (size_t)(min(tbase + 1, 48) * 64) * 128;
    kr0.v = *(const s16x8*)&ksrc[o1];
    kr1.v = *(const s16x8*)&ksrc[o1 + 8];
    #pragma unroll
    for (int c = 0; c < 2; ++c)
      #pragma unroll
      for (int n = 0; n < 2; ++n)
        vreg[c * 2 + n].v =
            *(const s16x8*)&vl[(size_t)(n * 16) * HW + tbase * 64 + c * 32];
  }
  asm volatile("s_waitcnt lgkmcnt(0)" ::: "memory");
  __builtin_amdgcn_s_barrier();

  for (int i = 0; i < 25; ++i) {
    int cur = i & 1;
    bool vld = (tbase + i) < 49;           // kh=1, i=24 is a dummy iteration
    int tV = min(tbase + i + 1, 48) * 64;  // V(i+1) base
    int tK = min(tbase + i + 2, 48) * 64;  // K(i+2) base

    if (vld) {
      // ---- QK: 4 ds_reads feed 8 MFMAs (both fragments share af) ----
      f32x4 st0[4], st1[4];
      #pragma unroll
      for (int tt = 0; tt < 4; ++tt) {
        S8 af;
        af.v = *(const s16x8*)&Klds[kh][cur][tt * 16 + lq][h * 8];
        st0[tt] = __builtin_amdgcn_mfma_f32_16x16x32_bf16(
            af.v, qf0.v, (f32x4){0.f, 0.f, 0.f, 0.f}, 0, 0, 0);
        st1[tt] = __builtin_amdgcn_mfma_f32_16x16x32_bf16(
            af.v, qf1.v, (f32x4){0.f, 0.f, 0.f, 0.f}, 0, 0, 0);
      }

      // ---- softmax numerators for both fragments ----
      #pragma unroll
      for (int tt = 0; tt < 4; ++tt) {
        float a0, a1, a2, a3, b0, b1, b2, b3;
        asm("v_exp_f32 %0, %1" : "=v"(a0) : "v"(st0[tt][0]));
        asm("v_exp_f32 %0, %1" : "=v"(a1) : "v"(st0[tt][1]));
        asm("v_exp_f32 %0, %1" : "=v"(a2) : "v"(st0[tt][2]));
        asm("v_exp_f32 %0, %1" : "=v"(a3) : "v"(st0[tt][3]));
        asm("v_exp_f32 %0, %1" : "=v"(b0) : "v"(st1[tt][0]));
        asm("v_exp_f32 %0, %1" : "=v"(b1) : "v"(st1[tt][1]));
        asm("v_exp_f32 %0, %1" : "=v"(b2) : "v"(st1[tt][2]));
        asm("v_exp_f32 %0, %1" : "=v"(b3) : "v"(st1[tt][3]));
        lsum0 += (a0 + a1) + (a2 + a3);
        lsum1 += (b0 + b1) + (b2 + b3);
        unsigned int lo0, hi0, lo1, hi1;
        asm("v_cvt_pk_bf16_f32 %0, %1, %2" : "=v"(lo0) : "v"(a0), "v"(a1));
        asm("v_cvt_pk_bf16_f32 %0, %1, %2" : "=v"(hi0) : "v"(a2), "v"(a3));
        asm("v_cvt_pk_bf16_f32 %0, %1, %2" : "=v"(lo1) : "v"(b0), "v"(b1));
        asm("v_cvt_pk_bf16_f32 %0, %1, %2" : "=v"(hi1) : "v"(b2), "v"(b3));
        unsigned long long pk0 = (unsigned long long)lo0 | ((unsigned long long)hi0 << 32);
        unsigned long long pk1 = (unsigned long long)lo1 | ((unsigned long long)hi1 << 32);
        *(unsigned long long*)&Plds[w][0][lq][tt * 16 + h * 4] = pk0;
        *(unsigned long long*)&Plds[w][1][lq][tt * 16 + h * 4] = pk1;
      }

      // ---- PV: 8 MFMAs, both fragments share vreg ----
      #pragma unroll
      for (int c = 0; c < 2; ++c) {
        S8 pf0, pf1;
        pf0.q[0] = *(const long long*)&Plds[w][0][lq][c * 32 + h * 8];
        pf0.q[1] = *(const long long*)&Plds[w][0][lq][c * 32 + h * 8 + 4];
        pf1.q[0] = *(const long long*)&Plds[w][1][lq][c * 32 + h * 8];
        pf1.q[1] = *(const long long*)&Plds[w][1][lq][c * 32 + h * 8 + 4];
        #pragma unroll
        for (int n = 0; n < 2; ++n) {
          oacc0[n] = __builtin_amdgcn_mfma_f32_16x16x32_bf16(
              vreg[c * 2 + n].v, pf0.v, oacc0[n], 0, 0, 0);
          oacc1[n] = __builtin_amdgcn_mfma_f32_16x16x32_bf16(
              vreg[c * 2 + n].v, pf1.v, oacc1[n], 0, 0, 0);
        }
      }
    }

    // ---- prefetch V(i+1) ----
    #pragma unroll
    for (int c = 0; c < 2; ++c)
      #pragma unroll
      for (int n = 0; n < 2; ++n)
        vreg[c * 2 + n].v =
            *(const s16x8*)&vl[(size_t)(n * 16) * HW + tV + c * 32];

    // ---- write K(i+1) to the other buffer; issue K(i+2) ----
    *(s16x8*)(kdst + ((i + 1) & 1) * KSTEP) = kr0.v;
    *(s16x8*)(kdst + ((i + 1) & 1) * KSTEP + 8) = kr1.v;
    kr0.v = *(const s16x8*)&ksrc[(size_t)tK * 128];
    kr1.v = *(const s16x8*)&ksrc[(size_t)tK * 128 + 8];

    asm volatile("s_waitcnt lgkmcnt(0)" ::: "memory");
    __builtin_amdgcn_s_barrier();
  }

  // ---- per-wave lsum reduce over h-lanes ----
  lsum0 += __shfl_xor(lsum0, 16);
  lsum0 += __shfl_xor(lsum0, 32);
  lsum1 += __shfl_xor(lsum1, 16);
  lsum1 += __shfl_xor(lsum1, 32);

  // ---- cross-kh combine via LDS (reuse dead Klds space) ----
  // blk(qg,f,n): 320 floats; lane (lq,h) owns 4 floats at lq*20 + h*4.
  float* fb = (float*)&Klds[0][0][0][0];
  if (kh == 1) {
    #pragma unroll
    for (int f = 0; f < 2; ++f) {
      f32x4* oacc = f ? oacc1 : oacc0;
      #pragma unroll
      for (int n = 0; n < 2; ++n)
        *(f32x4*)&fb[((qg * 2 + f) * 2 + n) * 320 + lq * 20 + h * 4] = oacc[n];
    }
    if (h == 0) {
      fb[2560 + qg * 32 + lq] = lsum0;
      fb[2560 + qg * 32 + 16 + lq] = lsum1;
    }
  }
  asm volatile("s_waitcnt lgkmcnt(0)" ::: "memory");
  __builtin_amdgcn_s_barrier();

  if (kh == 0) {
    #pragma unroll
    for (int f = 0; f < 2; ++f) {
      float lsum = (f ? lsum1 : lsum0) + fb[2560 + qg * 32 + f * 16 + lq];
      float inv = 1.f / lsum;
      f32x4* oacc = f ? oacc1 : oacc0;
      size_t obase = ((size_t)b * HW + q0 + f * 16 + lq) * 128 + hd * 32;
      #pragma unroll
      for (int n = 0; n < 2; ++n) {
        f32x4 rem = *(const f32x4*)&fb[((qg * 2 + f) * 2 + n) * 320 + lq * 20 + h * 4];
        us4 rh, rl;
        #pragma unroll
        for (int r = 0; r < 4; ++r) {
          float v = (oacc[n][r] + rem[r]) * inv;
          unsigned short hi = f2bf(v);
          rh[r] = hi;
          rl[r] = f2bf(v - bf2f(hi));
        }
        *(us4*)&aoHi[obase + n * 16 + h * 4] = rh;
        *(us4*)&aoLo[obase + n * 16 + h * 4] = rl;
      }
    }
  }
}

// ---------------------------------------------------------------------------
extern "C" void kernel_launch(void* const* d_in, const int* in_sizes, int n_in,
                              void* d_out, int out_size, void* d_ws, size_t ws_size,
                              hipStream_t stream) {
  const float* x    = (const float*)d_in[0];
  const float* dw_w = (const float*)d_in[1];
  const float* dw_b = (const float*)d_in[2];
  const float* ln_g = (const float*)d_in[3];
  const float* ln_b = (const float*)d_in[4];
  const float* offw = (const float*)d_in[5];
  const float* q_w  = (const float*)d_in[6];
  const float* q_b  = (const float*)d_in[7];
  const float* k_w  = (const float*)d_in[8];
  const float* k_b  = (const float*)d_in[9];
  const float* v_w  = (const float*)d_in[10];
  const float* v_b  = (const float*)d_in[11];
  const float* o_w  = (const float*)d_in[12];
  const float* o_b  = (const float*)d_in[13];

  const size_t NE = 1605632;  // 4*128*3136
  float* ws  = (float*)d_ws;
  float* q   = ws;                   // fp32 q [c][p] (offset branch)
  float* pos = q + NE;               // 50176 floats
  unsigned short* xsT  = (unsigned short*)(pos + 50176);  // sampled bf16 [p][128]
  unsigned short* qbT  = xsT + NE;   // q bf16 [p][128] scaled
  unsigned short* kbT  = qbT + NE;   // k bf16 [p][128]
  unsigned short* vb   = kbT + NE;   // v bf16 [c][p]
  unsigned short* aoHi = vb + NE;    // attn out hi bf16 [p][128]
  unsigned short* aoLo = aoHi + NE;  // attn out lo bf16 [p][128]
  unsigned short* Wq   = aoLo + NE;  // 16384 each
  unsigned short* Wk   = Wq + 16384;
  unsigned short* Wv   = Wk + 16384;
  unsigned short* WoH  = Wv + 16384;
  unsigned short* WoL  = WoH + 16384;
  float* out = (float*)d_out;

  wconv_kernel<<<dim3(64, 4), 256, 0, stream>>>(q_w, k_w, v_w, o_w,
                                                Wq, Wk, Wv, WoH, WoL);
  gemm_q_kernel<<<dim3(98, 8), 128, 0, stream>>>(x, Wq, q_b, q, qbT);
  offset_kernel<<<dim3(8, 56), 1024, 0, stream>>>(q, dw_w, dw_b, ln_g, ln_b, offw, pos);
  sample_kernel<<<dim3(392), 256, 0, stream>>>(x, pos, xsT);
  gemm_kv_kernel<<<dim3(98, 8), 128, 0, stream>>>(xsT, Wk, Wv, k_b, v_b, kbT, vb);
  attn_mfma_kernel<<<dim3(49, 16), 256, 0, stream>>>(qbT, kbT, vb, aoHi, aoLo);
  o_gemm_kernel<<<dim3(98, 8), 128, 0, stream>>>(aoHi, aoLo, WoH, WoL, o_b, out);
}